// Round 1
// baseline (311.758 us; speedup 1.0000x reference)
//
#include <hip/hip_runtime.h>

#define WSTRIDE 8704   // padded row stride for wab (8450 -> 8704, 16B aligned)

__device__ __forceinline__ float lrelu(float x) { return x > 0.0f ? x : 0.01f * x; }

// h0[b][j] = lrelu(sum_l z[b][l] * hW0[l][j] + hb0[j]);  B=128, L=16, HL=512
__global__ __launch_bounds__(256) void h0_kernel(const float* __restrict__ z,
                                                 const float* __restrict__ W,
                                                 const float* __restrict__ bias,
                                                 float* __restrict__ out) {
    int t = blockIdx.x * 256 + threadIdx.x;   // t = b*512 + j, 65536 total
    int b = t >> 9;
    int j = t & 511;
    float zr[16];
#pragma unroll
    for (int l = 0; l < 16; ++l) zr[l] = z[b * 16 + l];   // wave-uniform
    float acc = bias[j];
#pragma unroll
    for (int l = 0; l < 16; ++l) acc = fmaf(zr[l], W[l * 512 + j], acc);
    out[t] = lrelu(acc);
}

// C[128][512] = lrelu(A[128][512] @ W[512][512] + bias)
// grid 128 blocks x 128 thr: jt = blk&3 (j-tile 128), bt = blk>>2 (b-tile 4)
__global__ __launch_bounds__(128) void gemm512_lrelu(const float* __restrict__ A,
                                                     const float* __restrict__ W,
                                                     const float* __restrict__ bias,
                                                     float* __restrict__ out) {
    int jt = blockIdx.x & 3;
    int bt = blockIdx.x >> 2;        // 0..31
    int u = threadIdx.x & 63;
    int v = threadIdx.x >> 6;        // 0..1
    int j = jt * 128 + u * 2;
    int b0 = bt * 4 + v * 2;         // 2 b's per thread
    float acc00 = 0.f, acc01 = 0.f, acc10 = 0.f, acc11 = 0.f;
    for (int k4 = 0; k4 < 128; ++k4) {
        float4 A0 = *(const float4*)&A[(b0)*512 + k4 * 4];       // wave-uniform
        float4 A1 = *(const float4*)&A[(b0 + 1) * 512 + k4 * 4]; // wave-uniform
        float a0[4] = {A0.x, A0.y, A0.z, A0.w};
        float a1[4] = {A1.x, A1.y, A1.z, A1.w};
#pragma unroll
        for (int e = 0; e < 4; ++e) {
            float2 w = *(const float2*)&W[(k4 * 4 + e) * 512 + j];
            acc00 = fmaf(a0[e], w.x, acc00);
            acc01 = fmaf(a0[e], w.y, acc01);
            acc10 = fmaf(a1[e], w.x, acc10);
            acc11 = fmaf(a1[e], w.y, acc11);
        }
    }
    float2 bj = *(const float2*)&bias[j];
    float2 o0, o1;
    o0.x = lrelu(acc00 + bj.x); o0.y = lrelu(acc01 + bj.y);
    o1.x = lrelu(acc10 + bj.x); o1.y = lrelu(acc11 + bj.y);
    *(float2*)&out[(b0)*512 + j] = o0;
    *(float2*)&out[(b0 + 1) * 512 + j] = o1;
}

// wab[128][WSTRIDE] = A[128][512] @ W[512][8450] + bias  (only cols 0..8449 written)
// main blocks 0..1055: j-tile 128 (66 tiles cover 8448 cols), b-tile 8 (16 tiles)
// XCD swizzle: all 16 b-tiles of one j-tile land on the same XCD (W slice stays in L2)
// blocks 1056..1063: leftover columns 8448, 8449
__global__ __launch_bounds__(128) void wab_kernel(const float* __restrict__ A,
                                                  const float* __restrict__ W,
                                                  const float* __restrict__ bias,
                                                  float* __restrict__ wab) {
    int u = threadIdx.x & 63;
    int v = threadIdx.x >> 6;        // 0..1
    if (blockIdx.x >= 1056) {
        int b0 = (blockIdx.x - 1056) * 16 + v * 8;
        if (u < 2) {
            int jc = 8448 + u;
#pragma unroll
            for (int bb = 0; bb < 8; ++bb) {
                float acc = bias[jc];
                for (int k = 0; k < 512; ++k)
                    acc = fmaf(A[(b0 + bb) * 512 + k], W[k * 8450 + jc], acc);
                wab[(b0 + bb) * WSTRIDE + jc] = acc;
            }
        }
        return;
    }
    int xcd = blockIdx.x & 7;
    int s = blockIdx.x >> 3;         // 0..131
    int gid = xcd * 132 + s;         // 0..1055
    int jt = gid >> 4;               // 0..65
    int bt = gid & 15;               // 0..15
    int j = jt * 128 + u * 2;
    int b0 = bt * 8 + v * 4;         // 4 b's per thread
    float acc[4][2] = {};
    const float* Wj = W + j;
    for (int k4 = 0; k4 < 128; ++k4) {
        float av[4][4];
#pragma unroll
        for (int bb = 0; bb < 4; ++bb) {
            float4 t4 = *(const float4*)&A[(b0 + bb) * 512 + k4 * 4];  // wave-uniform
            av[bb][0] = t4.x; av[bb][1] = t4.y; av[bb][2] = t4.z; av[bb][3] = t4.w;
        }
#pragma unroll
        for (int e = 0; e < 4; ++e) {
            float2 w = *(const float2*)&Wj[(k4 * 4 + e) * 8450];  // 8B-aligned always
#pragma unroll
            for (int bb = 0; bb < 4; ++bb) {
                acc[bb][0] = fmaf(av[bb][e], w.x, acc[bb][0]);
                acc[bb][1] = fmaf(av[bb][e], w.y, acc[bb][1]);
            }
        }
    }
    float2 bj = *(const float2*)&bias[j];
#pragma unroll
    for (int bb = 0; bb < 4; ++bb) {
        float2 o;
        o.x = acc[bb][0] + bj.x;
        o.y = acc[bb][1] + bj.y;
        *(float2*)&wab[(b0 + bb) * WSTRIDE + j] = o;
    }
}

// Decoder: per (b,g): x=logP/3; l0: sin(30*(x*w0+b0)); l1,l2: sin(x@W+b); l3: x@w+b
// wab row layout: w0[0:64], b0[64], W1[65:4161], b1[4161:4225],
//                 W2[4225:8321], b2[8321:8385], w3[8385:8449], b3[8449]
// One wave per (b, g-half). Weights are wave-uniform -> SGPR loads.
__global__ __launch_bounds__(64) void decoder_kernel(const float* __restrict__ wab,
                                                     const float* __restrict__ logP,
                                                     float* __restrict__ out) {
    int b = blockIdx.x >> 1;
    int g = (blockIdx.x & 1) * 64 + threadIdx.x;
    const float* __restrict__ row = wab + b * WSTRIDE;
    bool act = g < 100;
    float x0 = act ? logP[b * 100 + g] * (1.0f / 3.0f) : 0.0f;
    float h[64], a[64];
    // layer 0: scale by 30 then sin
    float c0 = row[64];
#pragma unroll
    for (int jj = 0; jj < 64; ++jj)
        h[jj] = __sinf(30.0f * fmaf(x0, row[jj], c0));
    // layer 1
#pragma unroll
    for (int jj = 0; jj < 64; ++jj) a[jj] = row[4161 + jj];
#pragma unroll
    for (int i = 0; i < 64; ++i) {
        const float* wr = row + 65 + i * 64;
        float xi = h[i];
#pragma unroll
        for (int jj = 0; jj < 64; ++jj) a[jj] = fmaf(xi, wr[jj], a[jj]);
    }
#pragma unroll
    for (int jj = 0; jj < 64; ++jj) h[jj] = __sinf(a[jj]);
    // layer 2
#pragma unroll
    for (int jj = 0; jj < 64; ++jj) a[jj] = row[8321 + jj];
#pragma unroll
    for (int i = 0; i < 64; ++i) {
        const float* wr = row + 4225 + i * 64;
        float xi = h[i];
#pragma unroll
        for (int jj = 0; jj < 64; ++jj) a[jj] = fmaf(xi, wr[jj], a[jj]);
    }
#pragma unroll
    for (int jj = 0; jj < 64; ++jj) h[jj] = __sinf(a[jj]);
    // layer 3
    float accf = row[8449];
#pragma unroll
    for (int i = 0; i < 64; ++i) accf = fmaf(h[i], row[8385 + i], accf);
    if (act) out[b * 100 + g] = fmaf(accf, 500.0f, 1500.0f);
}

extern "C" void kernel_launch(void* const* d_in, const int* in_sizes, int n_in,
                              void* d_out, int out_size, void* d_ws, size_t ws_size,
                              hipStream_t stream) {
    const float* z    = (const float*)d_in[0];
    const float* logP = (const float*)d_in[1];
    const float* hW0  = (const float*)d_in[2];
    const float* hb0  = (const float*)d_in[3];
    const float* hW1  = (const float*)d_in[4];
    const float* hb1  = (const float*)d_in[5];
    const float* hW2  = (const float*)d_in[6];
    const float* hb2  = (const float*)d_in[7];
    const float* hWo  = (const float*)d_in[8];
    const float* hbo  = (const float*)d_in[9];
    float* out = (float*)d_out;

    float* wab = (float*)d_ws;               // 128*8704 floats = 4,456,448 B
    float* h0  = wab + 128 * WSTRIDE;        // 128*512 floats
    float* h1  = h0 + 128 * 512;
    float* h2  = h1 + 128 * 512;             // total ws use: 5.0 MiB

    h0_kernel<<<256, 256, 0, stream>>>(z, hW0, hb0, h0);
    gemm512_lrelu<<<128, 128, 0, stream>>>(h0, hW1, hb1, h1);
    gemm512_lrelu<<<128, 128, 0, stream>>>(h1, hW2, hb2, h2);
    wab_kernel<<<1064, 128, 0, stream>>>(h2, hWo, hbo, wab);
    decoder_kernel<<<256, 64, 0, stream>>>(wab, logP, out);
}

// Round 2
// 75.475 us; speedup vs baseline: 4.1306x; 4.1306x over previous
//
#include <hip/hip_runtime.h>

#define WSTRIDE 8704   // padded row stride for wab (8450 -> 8704, 16B aligned)
#define DSTR 68        // padded LDS stride in decoder (conflict-free b128)

__device__ __forceinline__ float lrelu(float x) { return x > 0.0f ? x : 0.01f * x; }

// h0T[j][b] = lrelu(sum_l z[b][l]*hW0[l][j] + hb0[j]);  B=128, L=16, HL=512
// block: b = blk>>1 (uniform), j = (blk&1)*256 + tid
__global__ __launch_bounds__(256) void h0T_kernel(const float* __restrict__ z,
                                                  const float* __restrict__ W,
                                                  const float* __restrict__ bias,
                                                  float* __restrict__ h0T) {
    int b = blockIdx.x >> 1;
    int j = (blockIdx.x & 1) * 256 + threadIdx.x;
    const float* __restrict__ zr = z + b * 16;   // uniform -> s_loads
    float acc = bias[j];
#pragma unroll
    for (int l = 0; l < 16; ++l) acc = fmaf(zr[l], W[l * 512 + j], acc);
    h0T[j * 128 + b] = lrelu(acc);
}

// O = lrelu(A@W + bias): reads At[k][128] (k=0..511), W[512][512], writes OT[j][128]
// block 256 thr = 4 waves; wave = k-quarter; tile 16 b x 64 j; LDS reduce.
__global__ __launch_bounds__(256) void gemmT_kernel(const float* __restrict__ At,
                                                    const float* __restrict__ W,
                                                    const float* __restrict__ bias,
                                                    float* __restrict__ OT) {
    __shared__ __align__(16) float red[4][64][20];
    int jt = blockIdx.x & 7;          // 8 j-tiles of 64
    int bt = blockIdx.x >> 3;         // 8 b-tiles of 16
    int lane = threadIdx.x & 63;
    int wid = __builtin_amdgcn_readfirstlane(threadIdx.x >> 6);
    int j = jt * 64 + lane;
    int b0 = bt * 16;
    float acc[16];
#pragma unroll
    for (int i = 0; i < 16; ++i) acc[i] = 0.f;
    int k0 = wid * 128;
#pragma unroll 4
    for (int kk = 0; kk < 128; ++kk) {
        int k = k0 + kk;
        const float* __restrict__ a = At + k * 128 + b0;  // uniform -> s_load_dwordx16
        float w = W[k * 512 + j];                          // coalesced dword
#pragma unroll
        for (int i = 0; i < 16; ++i) acc[i] = fmaf(a[i], w, acc[i]);
    }
#pragma unroll
    for (int t4 = 0; t4 < 4; ++t4)
        *(float4*)&red[wid][lane][t4 * 4] = make_float4(acc[t4*4], acc[t4*4+1], acc[t4*4+2], acc[t4*4+3]);
    __syncthreads();
    // reduce: thread t -> jj = t&63, bq = t>>6 (4 b's)
    int jj = threadIdx.x & 63;
    int bq = threadIdx.x >> 6;
    float4 s0 = *(const float4*)&red[0][jj][bq * 4];
    float4 s1 = *(const float4*)&red[1][jj][bq * 4];
    float4 s2 = *(const float4*)&red[2][jj][bq * 4];
    float4 s3 = *(const float4*)&red[3][jj][bq * 4];
    int jg = jt * 64 + jj;
    float bj = bias[jg];
    float4 o;
    o.x = lrelu(s0.x + s1.x + s2.x + s3.x + bj);
    o.y = lrelu(s0.y + s1.y + s2.y + s3.y + bj);
    o.z = lrelu(s0.z + s1.z + s2.z + s3.z + bj);
    o.w = lrelu(s0.w + s1.w + s2.w + s3.w + bj);
    *(float4*)&OT[jg * 128 + b0 + bq * 4] = o;
}

// wab[b][j] = sum_k A[b][k]*hWo[k][j] + hbo[j]; reads At[k][128], W[512][8450]
// tile 16 b x 64 j, 4 k-quarter waves + LDS reduce. XCD swizzle: all 8 b-tiles
// of a j-tile share blk%8 -> same XCD L2. Grid 1088 (17*8*8), jt>=133 idle.
__global__ __launch_bounds__(256) void wabT_kernel(const float* __restrict__ At,
                                                   const float* __restrict__ W,
                                                   const float* __restrict__ bias,
                                                   float* __restrict__ wab) {
    __shared__ __align__(16) float red[4][64][20];
    int r = blockIdx.x & 7;
    int m = blockIdx.x >> 3;
    int bt = m & 7;                   // 8 b-tiles of 16
    int jt = (m >> 3) * 8 + r;        // j-tile 0..135; jt%8 == blk%8 (XCD)
    if (jt >= 133) return;
    int lane = threadIdx.x & 63;
    int wid = __builtin_amdgcn_readfirstlane(threadIdx.x >> 6);
    int j = jt * 64 + lane;
    int jc = j < 8450 ? j : 8448;     // clamp for safe loads
    int b0 = bt * 16;
    float acc[16];
#pragma unroll
    for (int i = 0; i < 16; ++i) acc[i] = 0.f;
    int k0 = wid * 128;
#pragma unroll 4
    for (int kk = 0; kk < 128; ++kk) {
        int k = k0 + kk;
        const float* __restrict__ a = At + k * 128 + b0;  // uniform -> s_load_dwordx16
        float w = W[k * 8450 + jc];                        // coalesced dword
#pragma unroll
        for (int i = 0; i < 16; ++i) acc[i] = fmaf(a[i], w, acc[i]);
    }
#pragma unroll
    for (int t4 = 0; t4 < 4; ++t4)
        *(float4*)&red[wid][lane][t4 * 4] = make_float4(acc[t4*4], acc[t4*4+1], acc[t4*4+2], acc[t4*4+3]);
    __syncthreads();
    int jj = threadIdx.x & 63;
    int bq = threadIdx.x >> 6;
    float4 s0 = *(const float4*)&red[0][jj][bq * 4];
    float4 s1 = *(const float4*)&red[1][jj][bq * 4];
    float4 s2 = *(const float4*)&red[2][jj][bq * 4];
    float4 s3 = *(const float4*)&red[3][jj][bq * 4];
    int jg = jt * 64 + jj;
    if (jg < 8450) {
        float bj = bias[jg];
        float v0 = s0.x + s1.x + s2.x + s3.x + bj;
        float v1 = s0.y + s1.y + s2.y + s3.y + bj;
        float v2 = s0.z + s1.z + s2.z + s3.z + bj;
        float v3 = s0.w + s1.w + s2.w + s3.w + bj;
        wab[(b0 + bq * 4 + 0) * WSTRIDE + jg] = v0;
        wab[(b0 + bq * 4 + 1) * WSTRIDE + jg] = v1;
        wab[(b0 + bq * 4 + 2) * WSTRIDE + jg] = v2;
        wab[(b0 + bq * 4 + 3) * WSTRIDE + jg] = v3;
    }
}

// Decoder: per (b,g): x=logP/3; l0: sin(30*(x*w0+b0)); l1,l2: sin(x@W+b); l3: x@w+b
// wab row: w0[0:64], b0[64], W1[65:4161], b1[4161:4225], W2[4225:8321],
//          b2[8321:8385], w3[8385:8449], b3[8449]
// block = 4 waves: lane = g (64-g block), wave = j-quarter (16 j each).
// h state ping-pongs between two padded LDS buffers; weights via uniform s_loads.
__global__ __launch_bounds__(256) void decoder_kernel(const float* __restrict__ wab,
                                                      const float* __restrict__ logP,
                                                      float* __restrict__ out) {
    __shared__ __align__(16) float hA[64 * DSTR];
    __shared__ __align__(16) float hB[64 * DSTR];
    __shared__ float red[4][68];
    int b   = blockIdx.x >> 1;
    int gbl = blockIdx.x & 1;
    int lane = threadIdx.x & 63;
    int wid  = __builtin_amdgcn_readfirstlane(threadIdx.x >> 6);
    int jq = wid * 16;
    int g = gbl * 64 + lane;
    bool act = g < 100;
    const float* __restrict__ row = wab + b * WSTRIDE;
    float x0 = act ? logP[b * 100 + g] * (1.0f / 3.0f) : 0.0f;

    // layer 0: h0[g][j] = sin(30*(x0*w0[j] + b0)), j in [jq, jq+16)
    float c0 = row[64];
#pragma unroll
    for (int t4 = 0; t4 < 4; ++t4) {
        float4 v;
        v.x = __sinf(30.0f * fmaf(x0, row[jq + t4*4 + 0], c0));
        v.y = __sinf(30.0f * fmaf(x0, row[jq + t4*4 + 1], c0));
        v.z = __sinf(30.0f * fmaf(x0, row[jq + t4*4 + 2], c0));
        v.w = __sinf(30.0f * fmaf(x0, row[jq + t4*4 + 3], c0));
        *(float4*)&hA[lane * DSTR + jq + t4 * 4] = v;
    }
    __syncthreads();

    // layer 1: read hA, write hB
    {
        float a[16];
#pragma unroll
        for (int t = 0; t < 16; ++t) a[t] = row[4161 + jq + t];
        for (int i4 = 0; i4 < 16; ++i4) {
            float4 hv = *(const float4*)&hA[lane * DSTR + i4 * 4];
#pragma unroll
            for (int e = 0; e < 4; ++e) {
                int i = i4 * 4 + e;
                const float* __restrict__ wr = row + 65 + i * 64 + jq;  // uniform
                float hi = (&hv.x)[e];
#pragma unroll
                for (int t = 0; t < 16; ++t) a[t] = fmaf(hi, wr[t], a[t]);
            }
        }
#pragma unroll
        for (int t4 = 0; t4 < 4; ++t4) {
            float4 v;
            v.x = __sinf(a[t4*4 + 0]); v.y = __sinf(a[t4*4 + 1]);
            v.z = __sinf(a[t4*4 + 2]); v.w = __sinf(a[t4*4 + 3]);
            *(float4*)&hB[lane * DSTR + jq + t4 * 4] = v;
        }
    }
    __syncthreads();

    // layer 2: read hB, write hA
    {
        float a[16];
#pragma unroll
        for (int t = 0; t < 16; ++t) a[t] = row[8321 + jq + t];
        for (int i4 = 0; i4 < 16; ++i4) {
            float4 hv = *(const float4*)&hB[lane * DSTR + i4 * 4];
#pragma unroll
            for (int e = 0; e < 4; ++e) {
                int i = i4 * 4 + e;
                const float* __restrict__ wr = row + 4225 + i * 64 + jq;  // uniform
                float hi = (&hv.x)[e];
#pragma unroll
                for (int t = 0; t < 16; ++t) a[t] = fmaf(hi, wr[t], a[t]);
            }
        }
#pragma unroll
        for (int t4 = 0; t4 < 4; ++t4) {
            float4 v;
            v.x = __sinf(a[t4*4 + 0]); v.y = __sinf(a[t4*4 + 1]);
            v.z = __sinf(a[t4*4 + 2]); v.w = __sinf(a[t4*4 + 3]);
            *(float4*)&hA[lane * DSTR + jq + t4 * 4] = v;
        }
    }
    __syncthreads();

    // layer 3: partial dot over this wave's j-quarter, then cross-wave reduce
    float p = 0.f;
#pragma unroll
    for (int t4 = 0; t4 < 4; ++t4) {
        float4 hv = *(const float4*)&hA[lane * DSTR + jq + t4 * 4];
        p = fmaf(hv.x, row[8385 + jq + t4*4 + 0], p);
        p = fmaf(hv.y, row[8385 + jq + t4*4 + 1], p);
        p = fmaf(hv.z, row[8385 + jq + t4*4 + 2], p);
        p = fmaf(hv.w, row[8385 + jq + t4*4 + 3], p);
    }
    red[wid][lane] = p;
    __syncthreads();
    if (wid == 0 && act) {
        float s = red[0][lane] + red[1][lane] + red[2][lane] + red[3][lane] + row[8449];
        out[b * 100 + g] = fmaf(s, 500.0f, 1500.0f);
    }
}

extern "C" void kernel_launch(void* const* d_in, const int* in_sizes, int n_in,
                              void* d_out, int out_size, void* d_ws, size_t ws_size,
                              hipStream_t stream) {
    const float* z    = (const float*)d_in[0];
    const float* logP = (const float*)d_in[1];
    const float* hW0  = (const float*)d_in[2];
    const float* hb0  = (const float*)d_in[3];
    const float* hW1  = (const float*)d_in[4];
    const float* hb1  = (const float*)d_in[5];
    const float* hW2  = (const float*)d_in[6];
    const float* hb2  = (const float*)d_in[7];
    const float* hWo  = (const float*)d_in[8];
    const float* hbo  = (const float*)d_in[9];
    float* out = (float*)d_out;

    float* wab = (float*)d_ws;               // 128*8704 floats
    float* h0T = wab + 128 * WSTRIDE;        // 512*128 floats (transposed)
    float* h1T = h0T + 512 * 128;
    float* h2T = h1T + 512 * 128;            // total ws use ~5.24 MB

    h0T_kernel<<<256, 256, 0, stream>>>(z, hW0, hb0, h0T);
    gemmT_kernel<<<64, 256, 0, stream>>>(h0T, hW1, hb1, h1T);
    gemmT_kernel<<<64, 256, 0, stream>>>(h1T, hW2, hb2, h2T);
    wabT_kernel<<<1088, 256, 0, stream>>>(h2T, hWo, hbo, wab);
    decoder_kernel<<<256, 256, 0, stream>>>(wab, logP, out);
}

// Round 3
// 74.994 us; speedup vs baseline: 4.1571x; 1.0064x over previous
//
#include <hip/hip_runtime.h>

#define WSTRIDE 8704   // padded row stride for wab (8450 -> 8704, 16B aligned)
#define DSTR 68        // padded LDS stride in decoder (conflict-free b128)

__device__ __forceinline__ float lrelu(float x) { return x > 0.0f ? x : 0.01f * x; }

// h0T[j][b] = lrelu(sum_l z[b][l]*W0[l][j] + b0[j]); one block per j, lane = b
// W column loads are wave-uniform -> s_loads; stores coalesced along b.
__global__ __launch_bounds__(128) void h0T_kernel(const float* __restrict__ z,
                                                  const float* __restrict__ W,
                                                  const float* __restrict__ bias,
                                                  float* __restrict__ h0T) {
    int j = blockIdx.x;          // 0..511
    int b = threadIdx.x;         // 0..127
    float zr[16];
    *(float4*)&zr[0]  = *(const float4*)&z[b * 16 + 0];
    *(float4*)&zr[4]  = *(const float4*)&z[b * 16 + 4];
    *(float4*)&zr[8]  = *(const float4*)&z[b * 16 + 8];
    *(float4*)&zr[12] = *(const float4*)&z[b * 16 + 12];
    float acc = bias[j];
#pragma unroll
    for (int l = 0; l < 16; ++l) acc = fmaf(zr[l], W[l * 512 + j], acc);  // W: s_load
    h0T[j * 128 + b] = lrelu(acc);
}

// OT[j][b] = lrelu(sum_k At[k][b]*W[k][j] + bias[j]); At is [512][128]
// block 512 thr = 8 k-split waves; tile 64 j x 8 b; grid 128 (8 jt x 16 bt).
__global__ __launch_bounds__(512) void gemmT_kernel(const float* __restrict__ At,
                                                    const float* __restrict__ W,
                                                    const float* __restrict__ bias,
                                                    float* __restrict__ OT) {
    __shared__ float red[8][64][13];   // pad 13: conflict-free writes & reads
    int jt = blockIdx.x & 7;
    int bt = blockIdx.x >> 3;          // 0..15
    int lane = threadIdx.x & 63;
    int wid  = __builtin_amdgcn_readfirstlane(threadIdx.x >> 6);  // 0..7
    int j = jt * 64 + lane;
    int b0 = bt * 8;
    float acc[8] = {};
    int k0 = wid * 64;
#pragma unroll 4
    for (int kk = 0; kk < 64; ++kk) {
        int k = k0 + kk;
        const float* __restrict__ a = At + k * 128 + b0;   // uniform -> s_load_dwordx8
        float w = W[k * 512 + j];                          // coalesced dword
#pragma unroll
        for (int i = 0; i < 8; ++i) acc[i] = fmaf(a[i], w, acc[i]);
    }
#pragma unroll
    for (int i = 0; i < 8; ++i) red[wid][lane][i] = acc[i];
    __syncthreads();
    // reduce: bb-fast mapping -> stores in 32B chunks
    int jj = threadIdx.x >> 3;         // 0..63
    int bb = threadIdx.x & 7;
    float s = 0.f;
#pragma unroll
    for (int w = 0; w < 8; ++w) s += red[w][jj][bb];
    int jg = jt * 64 + jj;
    OT[jg * 128 + b0 + bb] = lrelu(s + bias[jg]);
}

// wab[b][j] = sum_k At[k][b]*hWo[k][j] + hbo[j]
// tile 128 j x 8 b, 4 k-split waves (256 thr). Grid 1153: main 1152 with
// jt = (idx>>4)*8 + (blk&7) so all 16 b-tiles of a j-tile share one XCD;
// tail block 1152 does j=8448,8449.
__global__ __launch_bounds__(256) void wabT_kernel(const float* __restrict__ At,
                                                   const float* __restrict__ W,
                                                   const float* __restrict__ bias,
                                                   float* __restrict__ wab) {
    __shared__ float red[4][128][13];  // 26.6 KB
    int tid = threadIdx.x;
    if (blockIdx.x == 1152) {          // tail: 2 leftover columns
        int b = tid & 127;
        int jc = 8448 + (tid >> 7);
        float acc = 0.f;
#pragma unroll 8
        for (int k = 0; k < 512; ++k)
            acc = fmaf(At[k * 128 + b], W[k * 8450 + jc], acc);  // W: s_load
        wab[b * WSTRIDE + jc] = acc + bias[jc];
        return;
    }
    int xcd = blockIdx.x & 7;
    int idx = blockIdx.x >> 3;         // 0..143
    int jt = (idx >> 4) * 8 + xcd;     // 0..71
    int bt = idx & 15;
    if (jt >= 66) return;
    int lane = tid & 63;
    int wid  = __builtin_amdgcn_readfirstlane(tid >> 6);  // 0..3
    int j = jt * 128 + lane * 2;
    int b0 = bt * 8;
    float acc[8][2] = {};
    int k0 = wid * 128;
#pragma unroll 4
    for (int kk = 0; kk < 128; ++kk) {
        int k = k0 + kk;
        const float* __restrict__ a = At + k * 128 + b0;   // uniform -> s_load_dwordx8
        float2 w = *(const float2*)&W[k * 8450 + j];       // coalesced 8B (always aligned)
#pragma unroll
        for (int i = 0; i < 8; ++i) {
            acc[i][0] = fmaf(a[i], w.x, acc[i][0]);
            acc[i][1] = fmaf(a[i], w.y, acc[i][1]);
        }
    }
#pragma unroll
    for (int i = 0; i < 8; ++i) {
        red[wid][lane * 2 + 0][i] = acc[i][0];   // stride 26 -> 2-way (free)
        red[wid][lane * 2 + 1][i] = acc[i][1];
    }
    __syncthreads();
    int jj = tid & 127;
    int half = tid >> 7;
    int jg = jt * 128 + jj;
    float bj = bias[jg];
#pragma unroll
    for (int q = 0; q < 4; ++q) {
        int bb = half * 4 + q;
        float s = red[0][jj][bb] + red[1][jj][bb] + red[2][jj][bb] + red[3][jj][bb];
        wab[(b0 + bb) * WSTRIDE + jg] = s + bj;   // coalesced along j
    }
}

// Decoder: per (b,g): x=logP/3; l0: sin(30*(x*w0+b0)); l1,l2: sin(x@W+b); l3: x@w+b
// wab row: w0[0:64], b0[64], W1[65:4161], b1[4161:4225], W2[4225:8321],
//          b2[8321:8385], w3[8385:8449], b3[8449]
// block = 4 waves: lane = g (64-g block), wave = j-quarter (16 j each).
__global__ __launch_bounds__(256) void decoder_kernel(const float* __restrict__ wab,
                                                      const float* __restrict__ logP,
                                                      float* __restrict__ out) {
    __shared__ __align__(16) float hA[64 * DSTR];
    __shared__ __align__(16) float hB[64 * DSTR];
    __shared__ float red[4][68];
    int b   = blockIdx.x >> 1;
    int gbl = blockIdx.x & 1;
    int lane = threadIdx.x & 63;
    int wid  = __builtin_amdgcn_readfirstlane(threadIdx.x >> 6);
    int jq = wid * 16;
    int g = gbl * 64 + lane;
    bool act = g < 100;
    const float* __restrict__ row = wab + b * WSTRIDE;
    float x0 = act ? logP[b * 100 + g] * (1.0f / 3.0f) : 0.0f;

    // layer 0
    float c0 = row[64];
#pragma unroll
    for (int t4 = 0; t4 < 4; ++t4) {
        float4 v;
        v.x = __sinf(30.0f * fmaf(x0, row[jq + t4*4 + 0], c0));
        v.y = __sinf(30.0f * fmaf(x0, row[jq + t4*4 + 1], c0));
        v.z = __sinf(30.0f * fmaf(x0, row[jq + t4*4 + 2], c0));
        v.w = __sinf(30.0f * fmaf(x0, row[jq + t4*4 + 3], c0));
        *(float4*)&hA[lane * DSTR + jq + t4 * 4] = v;
    }
    __syncthreads();

    // layer 1: read hA, write hB
    {
        float a[16];
#pragma unroll
        for (int t = 0; t < 16; ++t) a[t] = row[4161 + jq + t];
#pragma unroll 4
        for (int i4 = 0; i4 < 16; ++i4) {
            float4 hv = *(const float4*)&hA[lane * DSTR + i4 * 4];
#pragma unroll
            for (int e = 0; e < 4; ++e) {
                int i = i4 * 4 + e;
                const float* __restrict__ wr = row + 65 + i * 64 + jq;  // s_load_dwordx16
                float hi = (&hv.x)[e];
#pragma unroll
                for (int t = 0; t < 16; ++t) a[t] = fmaf(hi, wr[t], a[t]);
            }
        }
#pragma unroll
        for (int t4 = 0; t4 < 4; ++t4) {
            float4 v;
            v.x = __sinf(a[t4*4 + 0]); v.y = __sinf(a[t4*4 + 1]);
            v.z = __sinf(a[t4*4 + 2]); v.w = __sinf(a[t4*4 + 3]);
            *(float4*)&hB[lane * DSTR + jq + t4 * 4] = v;
        }
    }
    __syncthreads();

    // layer 2: read hB, write hA
    {
        float a[16];
#pragma unroll
        for (int t = 0; t < 16; ++t) a[t] = row[8321 + jq + t];
#pragma unroll 4
        for (int i4 = 0; i4 < 16; ++i4) {
            float4 hv = *(const float4*)&hB[lane * DSTR + i4 * 4];
#pragma unroll
            for (int e = 0; e < 4; ++e) {
                int i = i4 * 4 + e;
                const float* __restrict__ wr = row + 4225 + i * 64 + jq;
                float hi = (&hv.x)[e];
#pragma unroll
                for (int t = 0; t < 16; ++t) a[t] = fmaf(hi, wr[t], a[t]);
            }
        }
#pragma unroll
        for (int t4 = 0; t4 < 4; ++t4) {
            float4 v;
            v.x = __sinf(a[t4*4 + 0]); v.y = __sinf(a[t4*4 + 1]);
            v.z = __sinf(a[t4*4 + 2]); v.w = __sinf(a[t4*4 + 3]);
            *(float4*)&hA[lane * DSTR + jq + t4 * 4] = v;
        }
    }
    __syncthreads();

    // layer 3
    float p = 0.f;
#pragma unroll
    for (int t4 = 0; t4 < 4; ++t4) {
        float4 hv = *(const float4*)&hA[lane * DSTR + jq + t4 * 4];
        p = fmaf(hv.x, row[8385 + jq + t4*4 + 0], p);
        p = fmaf(hv.y, row[8385 + jq + t4*4 + 1], p);
        p = fmaf(hv.z, row[8385 + jq + t4*4 + 2], p);
        p = fmaf(hv.w, row[8385 + jq + t4*4 + 3], p);
    }
    red[wid][lane] = p;
    __syncthreads();
    if (wid == 0 && act) {
        float s = red[0][lane] + red[1][lane] + red[2][lane] + red[3][lane] + row[8449];
        out[b * 100 + g] = fmaf(s, 500.0f, 1500.0f);
    }
}

extern "C" void kernel_launch(void* const* d_in, const int* in_sizes, int n_in,
                              void* d_out, int out_size, void* d_ws, size_t ws_size,
                              hipStream_t stream) {
    const float* z    = (const float*)d_in[0];
    const float* logP = (const float*)d_in[1];
    const float* hW0  = (const float*)d_in[2];
    const float* hb0  = (const float*)d_in[3];
    const float* hW1  = (const float*)d_in[4];
    const float* hb1  = (const float*)d_in[5];
    const float* hW2  = (const float*)d_in[6];
    const float* hb2  = (const float*)d_in[7];
    const float* hWo  = (const float*)d_in[8];
    const float* hbo  = (const float*)d_in[9];
    float* out = (float*)d_out;

    float* wab = (float*)d_ws;               // 128*8704 floats
    float* h0T = wab + 128 * WSTRIDE;        // 512*128 floats (transposed)
    float* h1T = h0T + 512 * 128;
    float* h2T = h1T + 512 * 128;

    h0T_kernel<<<512, 128, 0, stream>>>(z, hW0, hb0, h0T);
    gemmT_kernel<<<128, 512, 0, stream>>>(h0T, hW1, hb1, h1T);
    gemmT_kernel<<<128, 512, 0, stream>>>(h1T, hW2, hb2, h2T);
    wabT_kernel<<<1153, 256, 0, stream>>>(h2T, hWo, hbo, wab);
    decoder_kernel<<<256, 256, 0, stream>>>(wab, logP, out);
}

// Round 4
// 72.713 us; speedup vs baseline: 4.2875x; 1.0314x over previous
//
#include <hip/hip_runtime.h>

#define WSTRIDE 8704   // padded row stride for wab (8450 -> 8704, 16B aligned)
#define GSTR 65        // decoder h-LDS stride: lane-consecutive -> conflict-free

__device__ __forceinline__ float lrelu(float x) { return x > 0.0f ? x : 0.01f * x; }

// h0T[j][b] = lrelu(sum_l z[b][l]*W0[l][j] + b0[j]); one block per j, lane = b
__global__ __launch_bounds__(128) void h0T_kernel(const float* __restrict__ z,
                                                  const float* __restrict__ W,
                                                  const float* __restrict__ bias,
                                                  float* __restrict__ h0T) {
    int j = blockIdx.x;          // 0..511
    int b = threadIdx.x;         // 0..127
    float zr[16];
    *(float4*)&zr[0]  = *(const float4*)&z[b * 16 + 0];
    *(float4*)&zr[4]  = *(const float4*)&z[b * 16 + 4];
    *(float4*)&zr[8]  = *(const float4*)&z[b * 16 + 8];
    *(float4*)&zr[12] = *(const float4*)&z[b * 16 + 12];
    float acc = bias[j];
#pragma unroll
    for (int l = 0; l < 16; ++l) acc = fmaf(zr[l], W[l * 512 + j], acc);
    h0T[j * 128 + b] = lrelu(acc);
}

// OT[j][b] = lrelu(sum_k At[k][b]*W[k][j] + bias[j])
// tile 64 j x 4 b, k-split 4 (256 thr); At slice staged in LDS (broadcast reads).
// grid 256 = 8 jt x 32 bt.
__global__ __launch_bounds__(256) void gemmT_kernel(const float* __restrict__ At,
                                                    const float* __restrict__ W,
                                                    const float* __restrict__ bias,
                                                    float* __restrict__ OT) {
    __shared__ __align__(16) float As[512][4];   // 8 KB
    __shared__ float red[4][64][5];              // 5 KB
    int jt = blockIdx.x & 7;
    int bt = blockIdx.x >> 3;          // 0..31
    int tid = threadIdx.x;
    int lane = tid & 63;
    int wid  = __builtin_amdgcn_readfirstlane(tid >> 6);  // 0..3
    int b0 = bt * 4;
    // stage At[0:512][b0:b0+4] -> As (coalesced float2)
#pragma unroll
    for (int r = 0; r < 4; ++r) {
        int p = r * 256 + tid;         // 0..1023
        int k = p >> 1, q = p & 1;
        *(float2*)&As[k][q * 2] = *(const float2*)&At[k * 128 + b0 + q * 2];
    }
    __syncthreads();
    int j = jt * 64 + lane;
    float acc[4] = {};
    int k0 = wid * 128;
#pragma unroll 8
    for (int kk = 0; kk < 128; ++kk) {
        int k = k0 + kk;
        float4 a = *(const float4*)&As[k][0];   // LDS broadcast
        float w = W[k * 512 + j];               // coalesced dword
        acc[0] = fmaf(a.x, w, acc[0]);
        acc[1] = fmaf(a.y, w, acc[1]);
        acc[2] = fmaf(a.z, w, acc[2]);
        acc[3] = fmaf(a.w, w, acc[3]);
    }
#pragma unroll
    for (int i = 0; i < 4; ++i) red[wid][lane][i] = acc[i];
    __syncthreads();
    int jj = tid >> 2;                 // 0..63
    int bb = tid & 3;
    float s = red[0][jj][bb] + red[1][jj][bb] + red[2][jj][bb] + red[3][jj][bb];
    int jg = jt * 64 + jj;
    OT[jg * 128 + b0 + bb] = lrelu(s + bias[jg]);
}

// wab[b][j] = sum_k At[k][b]*hWo[k][j] + hbo[j]
// tile 128 j x 16 b, k-split 4 (256 thr). At slice in LDS (broadcast), W streamed
// as float2 (2 j/lane). Grid 529: 528 main (XCD-grouped: 8 b-tiles of a j-tile
// contiguous within one XCD) + tail block for j=8448,8449.
__global__ __launch_bounds__(256) void wabT_kernel(const float* __restrict__ At,
                                                   const float* __restrict__ W,
                                                   const float* __restrict__ bias,
                                                   float* __restrict__ wab) {
    __shared__ __align__(16) float As[512][16];  // 32 KB
    __shared__ float red[4][64][33];             // 33.8 KB (stride 33: conflict-free)
    int tid = threadIdx.x;
    if (blockIdx.x == 528) {           // tail: 2 leftover columns
        int b = tid & 127;
        int jc = 8448 + (tid >> 7);
        float a0 = 0.f, a1 = 0.f, a2 = 0.f, a3 = 0.f;
#pragma unroll 4
        for (int k4 = 0; k4 < 128; ++k4) {
            a0 = fmaf(At[(k4*4+0) * 128 + b], W[(k4*4+0) * 8450 + jc], a0);
            a1 = fmaf(At[(k4*4+1) * 128 + b], W[(k4*4+1) * 8450 + jc], a1);
            a2 = fmaf(At[(k4*4+2) * 128 + b], W[(k4*4+2) * 8450 + jc], a2);
            a3 = fmaf(At[(k4*4+3) * 128 + b], W[(k4*4+3) * 8450 + jc], a3);
        }
        wab[b * WSTRIDE + jc] = a0 + a1 + a2 + a3 + bias[jc];
        return;
    }
    int v = (blockIdx.x & 7) * 66 + (blockIdx.x >> 3);  // 0..527
    int jt = v >> 3;                   // 0..65
    int bt = v & 7;                    // 0..7
    int lane = tid & 63;
    int wid  = __builtin_amdgcn_readfirstlane(tid >> 6);  // 0..3
    int b0 = bt * 16;
    // stage At[0:512][b0:b0+16] -> As (coalesced float2, 16 rounds)
#pragma unroll
    for (int r = 0; r < 16; ++r) {
        int p = r * 256 + tid;         // 0..4095
        int k = p >> 3, q = p & 7;
        *(float2*)&As[k][q * 2] = *(const float2*)&At[k * 128 + b0 + q * 2];
    }
    __syncthreads();
    int j0 = jt * 128 + lane * 2;
    float acc[16][2] = {};
    int k0 = wid * 128;
#pragma unroll 4
    for (int kk = 0; kk < 128; ++kk) {
        int k = k0 + kk;
        float4 a0 = *(const float4*)&As[k][0];    // LDS broadcast x4
        float4 a1 = *(const float4*)&As[k][4];
        float4 a2 = *(const float4*)&As[k][8];
        float4 a3 = *(const float4*)&As[k][12];
        float2 w = *(const float2*)&W[k * 8450 + j0];  // 8B aligned (j0 even)
        float av[16] = {a0.x,a0.y,a0.z,a0.w, a1.x,a1.y,a1.z,a1.w,
                        a2.x,a2.y,a2.z,a2.w, a3.x,a3.y,a3.z,a3.w};
#pragma unroll
        for (int bb = 0; bb < 16; ++bb) {
            acc[bb][0] = fmaf(av[bb], w.x, acc[bb][0]);
            acc[bb][1] = fmaf(av[bb], w.y, acc[bb][1]);
        }
    }
#pragma unroll
    for (int bb = 0; bb < 16; ++bb) {
        red[wid][lane][bb * 2 + 0] = acc[bb][0];
        red[wid][lane][bb * 2 + 1] = acc[bb][1];
    }
    __syncthreads();
    // reduce: thread t -> jj = t>>1 (0..127), bh = t&1 (8 b's each)
    int jj = tid >> 1;
    int bh = tid & 1;
    int lane_r = jj >> 1;
    int jl = jj & 1;
    int jg = jt * 128 + jj;
    float bj = bias[jg];
#pragma unroll
    for (int bq = 0; bq < 8; ++bq) {
        int bb = bh * 8 + bq;
        int idx = bb * 2 + jl;
        float s = red[0][lane_r][idx] + red[1][lane_r][idx]
                + red[2][lane_r][idx] + red[3][lane_r][idx];
        wab[(b0 + bb) * WSTRIDE + jg] = s + bj;
    }
}

// Decoder with LDS-staged weights + transposed h state (h[j][lane]).
// wab row: w0[0:64], b0[64], W1[65:4161], b1[4161:4225], W2[4225:8321],
//          b2[8321:8385], w3[8385:8449], b3[8449]
__global__ __launch_bounds__(256) void decoder_kernel(const float* __restrict__ wab,
                                                      const float* __restrict__ logP,
                                                      float* __restrict__ out) {
    __shared__ __align__(16) float Wl[64 * 64];   // 16 KB staged W1 then W2
    __shared__ float hX[64 * GSTR];               // 16.6 KB, h[j][lane]
    __shared__ float hY[64 * GSTR];
    __shared__ float red[4][68];
    int b   = blockIdx.x >> 1;
    int gbl = blockIdx.x & 1;
    int tid = threadIdx.x;
    int lane = tid & 63;
    int wid  = __builtin_amdgcn_readfirstlane(tid >> 6);
    int jq = wid * 16;
    int g = gbl * 64 + lane;
    bool act = g < 100;
    const float* __restrict__ row = wab + b * WSTRIDE;
    float x0 = act ? logP[b * 100 + g] * (1.0f / 3.0f) : 0.0f;

    // layer 0: h[j][lane] = sin(30*(x0*w0[j] + b0)), j in this wave's quarter
    float c0 = row[64];
#pragma unroll
    for (int t = 0; t < 16; ++t)
        hX[(jq + t) * GSTR + lane] = __sinf(30.0f * fmaf(x0, row[jq + t], c0));
    // stage W1 (coalesced b32)
#pragma unroll
    for (int r = 0; r < 16; ++r) {
        int idx = r * 256 + tid;
        Wl[idx] = row[65 + idx];
    }
    __syncthreads();

    // layer 1: a[j] = sum_i h_i * W1[i][j]; read hX, write hY
    {
        float a[16];
#pragma unroll
        for (int t = 0; t < 16; ++t) a[t] = row[4161 + jq + t];
#pragma unroll 4
        for (int i = 0; i < 64; ++i) {
            float hi = hX[i * GSTR + lane];          // stride-1: conflict-free
            const float* wr = &Wl[i * 64 + jq];      // wave-uniform broadcast
            float4 w0 = *(const float4*)&wr[0];
            float4 w1 = *(const float4*)&wr[4];
            float4 w2 = *(const float4*)&wr[8];
            float4 w3 = *(const float4*)&wr[12];
            a[0]  = fmaf(hi, w0.x, a[0]);  a[1]  = fmaf(hi, w0.y, a[1]);
            a[2]  = fmaf(hi, w0.z, a[2]);  a[3]  = fmaf(hi, w0.w, a[3]);
            a[4]  = fmaf(hi, w1.x, a[4]);  a[5]  = fmaf(hi, w1.y, a[5]);
            a[6]  = fmaf(hi, w1.z, a[6]);  a[7]  = fmaf(hi, w1.w, a[7]);
            a[8]  = fmaf(hi, w2.x, a[8]);  a[9]  = fmaf(hi, w2.y, a[9]);
            a[10] = fmaf(hi, w2.z, a[10]); a[11] = fmaf(hi, w2.w, a[11]);
            a[12] = fmaf(hi, w3.x, a[12]); a[13] = fmaf(hi, w3.y, a[13]);
            a[14] = fmaf(hi, w3.z, a[14]); a[15] = fmaf(hi, w3.w, a[15]);
        }
#pragma unroll
        for (int t = 0; t < 16; ++t) hY[(jq + t) * GSTR + lane] = __sinf(a[t]);
    }
    __syncthreads();
    // stage W2 over Wl
#pragma unroll
    for (int r = 0; r < 16; ++r) {
        int idx = r * 256 + tid;
        Wl[idx] = row[4225 + idx];
    }
    __syncthreads();

    // layer 2: read hY, write hX
    {
        float a[16];
#pragma unroll
        for (int t = 0; t < 16; ++t) a[t] = row[8321 + jq + t];
#pragma unroll 4
        for (int i = 0; i < 64; ++i) {
            float hi = hY[i * GSTR + lane];
            const float* wr = &Wl[i * 64 + jq];
            float4 w0 = *(const float4*)&wr[0];
            float4 w1 = *(const float4*)&wr[4];
            float4 w2 = *(const float4*)&wr[8];
            float4 w3 = *(const float4*)&wr[12];
            a[0]  = fmaf(hi, w0.x, a[0]);  a[1]  = fmaf(hi, w0.y, a[1]);
            a[2]  = fmaf(hi, w0.z, a[2]);  a[3]  = fmaf(hi, w0.w, a[3]);
            a[4]  = fmaf(hi, w1.x, a[4]);  a[5]  = fmaf(hi, w1.y, a[5]);
            a[6]  = fmaf(hi, w1.z, a[6]);  a[7]  = fmaf(hi, w1.w, a[7]);
            a[8]  = fmaf(hi, w2.x, a[8]);  a[9]  = fmaf(hi, w2.y, a[9]);
            a[10] = fmaf(hi, w2.z, a[10]); a[11] = fmaf(hi, w2.w, a[11]);
            a[12] = fmaf(hi, w3.x, a[12]); a[13] = fmaf(hi, w3.y, a[13]);
            a[14] = fmaf(hi, w3.z, a[14]); a[15] = fmaf(hi, w3.w, a[15]);
        }
#pragma unroll
        for (int t = 0; t < 16; ++t) hX[(jq + t) * GSTR + lane] = __sinf(a[t]);
    }
    __syncthreads();

    // layer 3: partial dot over this wave's j-quarter, cross-wave reduce
    float p = 0.f;
#pragma unroll
    for (int t = 0; t < 16; ++t)
        p = fmaf(hX[(jq + t) * GSTR + lane], row[8385 + jq + t], p);
    red[wid][lane] = p;
    __syncthreads();
    if (wid == 0 && act) {
        float s = red[0][lane] + red[1][lane] + red[2][lane] + red[3][lane] + row[8449];
        out[b * 100 + g] = fmaf(s, 500.0f, 1500.0f);
    }
}

extern "C" void kernel_launch(void* const* d_in, const int* in_sizes, int n_in,
                              void* d_out, int out_size, void* d_ws, size_t ws_size,
                              hipStream_t stream) {
    const float* z    = (const float*)d_in[0];
    const float* logP = (const float*)d_in[1];
    const float* hW0  = (const float*)d_in[2];
    const float* hb0  = (const float*)d_in[3];
    const float* hW1  = (const float*)d_in[4];
    const float* hb1  = (const float*)d_in[5];
    const float* hW2  = (const float*)d_in[6];
    const float* hb2  = (const float*)d_in[7];
    const float* hWo  = (const float*)d_in[8];
    const float* hbo  = (const float*)d_in[9];
    float* out = (float*)d_out;

    float* wab = (float*)d_ws;               // 128*8704 floats
    float* h0T = wab + 128 * WSTRIDE;        // 512*128 floats (transposed)
    float* h1T = h0T + 512 * 128;
    float* h2T = h1T + 512 * 128;

    h0T_kernel<<<512, 128, 0, stream>>>(z, hW0, hb0, h0T);
    gemmT_kernel<<<256, 256, 0, stream>>>(h0T, hW1, hb1, h1T);
    gemmT_kernel<<<256, 256, 0, stream>>>(h1T, hW2, hb2, h2T);
    wabT_kernel<<<529, 256, 0, stream>>>(h2T, hWo, hbo, wab);
    decoder_kernel<<<256, 256, 0, stream>>>(wab, logP, out);
}

// Round 5
// 61.084 us; speedup vs baseline: 5.1038x; 1.1904x over previous
//
#include <hip/hip_runtime.h>

#define WSTRIDE 8704   // padded row stride for wab (8450 -> 8704, 16B aligned)
#define GSTR 65        // decoder h-LDS stride: lane-consecutive -> conflict-free

__device__ __forceinline__ float lrelu(float x) { return x > 0.0f ? x : 0.01f * x; }

// h0T[j][b] = lrelu(sum_l z[b][l]*W0[l][j] + b0[j]); one block per j, lane = b
__global__ __launch_bounds__(128) void h0T_kernel(const float* __restrict__ z,
                                                  const float* __restrict__ W,
                                                  const float* __restrict__ bias,
                                                  float* __restrict__ h0T) {
    int j = blockIdx.x;          // 0..511
    int b = threadIdx.x;         // 0..127
    float zr[16];
    *(float4*)&zr[0]  = *(const float4*)&z[b * 16 + 0];
    *(float4*)&zr[4]  = *(const float4*)&z[b * 16 + 4];
    *(float4*)&zr[8]  = *(const float4*)&z[b * 16 + 8];
    *(float4*)&zr[12] = *(const float4*)&z[b * 16 + 12];
    float acc = bias[j];
#pragma unroll
    for (int l = 0; l < 16; ++l) acc = fmaf(zr[l], W[l * 512 + j], acc);
    h0T[j * 128 + b] = lrelu(acc);
}

// OT[j][b] = lrelu(sum_k At[k][b]*W[k][j] + bias[j])
// tile 64 j x 4 b, k-split 8 (512 thr); At slice staged in LDS (broadcast reads).
// grid 256 = 8 jt x 32 bt.
__global__ __launch_bounds__(512) void gemmT_kernel(const float* __restrict__ At,
                                                    const float* __restrict__ W,
                                                    const float* __restrict__ bias,
                                                    float* __restrict__ OT) {
    __shared__ __align__(16) float As[512][4];   // 8 KB
    __shared__ float red[8][64][5];              // 10 KB
    int jt = blockIdx.x & 7;
    int bt = blockIdx.x >> 3;          // 0..31
    int tid = threadIdx.x;
    int lane = tid & 63;
    int wid  = __builtin_amdgcn_readfirstlane(tid >> 6);  // 0..7
    int b0 = bt * 4;
#pragma unroll
    for (int r = 0; r < 2; ++r) {
        int p = r * 512 + tid;         // 0..1023
        int k = p >> 1, q = p & 1;
        *(float2*)&As[k][q * 2] = *(const float2*)&At[k * 128 + b0 + q * 2];
    }
    __syncthreads();
    int j = jt * 64 + lane;
    float acc[4] = {};
    int k0 = wid * 64;
#pragma unroll 8
    for (int kk = 0; kk < 64; ++kk) {
        int k = k0 + kk;
        float4 a = *(const float4*)&As[k][0];   // LDS broadcast
        float w = W[k * 512 + j];               // coalesced dword
        acc[0] = fmaf(a.x, w, acc[0]);
        acc[1] = fmaf(a.y, w, acc[1]);
        acc[2] = fmaf(a.z, w, acc[2]);
        acc[3] = fmaf(a.w, w, acc[3]);
    }
#pragma unroll
    for (int i = 0; i < 4; ++i) red[wid][lane][i] = acc[i];
    __syncthreads();
    if (tid < 256) {
        int jj = tid >> 2;             // 0..63
        int bb = tid & 3;
        float s = 0.f;
#pragma unroll
        for (int w = 0; w < 8; ++w) s += red[w][jj][bb];
        int jg = jt * 64 + jj;
        OT[jg * 128 + b0 + bb] = lrelu(s + bias[jg]);
    }
}

// --- wabT: register double-buffered pipeline ---
__device__ __forceinline__ void loadg(const float As[][16], const float* __restrict__ W,
                                      int k0, int g, int j0,
                                      float4 (&aa)[4][4], float2 (&ww)[4]) {
    int kb = k0 + g * 4;
#pragma unroll
    for (int kk = 0; kk < 4; ++kk) {
        const float* asr = As[kb + kk];
        aa[kk][0] = *(const float4*)&asr[0];
        aa[kk][1] = *(const float4*)&asr[4];
        aa[kk][2] = *(const float4*)&asr[8];
        aa[kk][3] = *(const float4*)&asr[12];
        ww[kk] = *(const float2*)&W[(kb + kk) * 8450 + j0];
    }
}

__device__ __forceinline__ void compg(const float4 (&aa)[4][4], const float2 (&ww)[4],
                                      float (&acc)[16][2]) {
#pragma unroll
    for (int kk = 0; kk < 4; ++kk) {
#pragma unroll
        for (int q = 0; q < 4; ++q) {
            const float4 a = aa[kk][q];
            const float av[4] = {a.x, a.y, a.z, a.w};
#pragma unroll
            for (int e = 0; e < 4; ++e) {
                acc[q * 4 + e][0] = fmaf(av[e], ww[kk].x, acc[q * 4 + e][0]);
                acc[q * 4 + e][1] = fmaf(av[e], ww[kk].y, acc[q * 4 + e][1]);
            }
        }
    }
}

// wab[b][j] = sum_k At[k][b]*hWo[k][j] + hbo[j]
// tile 128 j x 16 b, k-split 4 (256 thr). At slice in LDS (broadcast), W streamed
// as float2 with one-group register prefetch. Grid 536 = 67 jt x 8 bt,
// XCD-grouped so b-tiles of a j-tile stay on one XCD. jt=66 clamps (j>=8450 masked).
__global__ __launch_bounds__(256, 2) void wabT_kernel(const float* __restrict__ At,
                                                      const float* __restrict__ W,
                                                      const float* __restrict__ bias,
                                                      float* __restrict__ wab) {
    __shared__ __align__(16) float As[512][16];  // 32 KB
    __shared__ float red[4][64][33];             // 33.8 KB
    int tid = threadIdx.x;
    int v = (blockIdx.x & 7) * 67 + (blockIdx.x >> 3);  // 0..535
    int jt = v >> 3;                   // 0..66
    int bt = v & 7;                    // 0..7
    int lane = tid & 63;
    int wid  = __builtin_amdgcn_readfirstlane(tid >> 6);  // 0..3
    int b0 = bt * 16;
    // stage At[0:512][b0:b0+16] -> As (coalesced float2)
#pragma unroll
    for (int r = 0; r < 16; ++r) {
        int p = r * 256 + tid;         // 0..4095
        int k = p >> 3, q = p & 7;
        *(float2*)&As[k][q * 2] = *(const float2*)&At[k * 128 + b0 + q * 2];
    }
    __syncthreads();
    int j0r = jt * 128 + lane * 2;
    int j0 = j0r < 8448 ? j0r : 8448;  // clamp (even -> float2 stays aligned)
    float acc[16][2] = {};
    int k0 = wid * 128;
    float4 aA[4][4], aB[4][4];
    float2 wA[4], wB[4];
    loadg(As, W, k0, 0, j0, aA, wA);
    for (int it = 0; it < 15; ++it) {
        loadg(As, W, k0, 2 * it + 1, j0, aB, wB);
        compg(aA, wA, acc);
        loadg(As, W, k0, 2 * it + 2, j0, aA, wA);
        compg(aB, wB, acc);
    }
    loadg(As, W, k0, 31, j0, aB, wB);
    compg(aA, wA, acc);
    compg(aB, wB, acc);
#pragma unroll
    for (int bb = 0; bb < 16; ++bb) {
        red[wid][lane][bb * 2 + 0] = acc[bb][0];
        red[wid][lane][bb * 2 + 1] = acc[bb][1];
    }
    __syncthreads();
    // reduce: thread t -> jj = t>>1 (0..127), bh = t&1 (8 b's each)
    int jj = tid >> 1;
    int bh = tid & 1;
    int lane_r = jj >> 1;
    int jl = jj & 1;
    int jg = jt * 128 + jj;
    if (jg < 8450) {
        float bj = bias[jg];
#pragma unroll
        for (int bq = 0; bq < 8; ++bq) {
            int bb = bh * 8 + bq;
            int idx = bb * 2 + jl;
            float s = red[0][lane_r][idx] + red[1][lane_r][idx]
                    + red[2][lane_r][idx] + red[3][lane_r][idx];
            wab[(b0 + bb) * WSTRIDE + jg] = s + bj;
        }
    }
}

// Decoder: 8 waves/block, wave owns 8 j; h state transposed in LDS (h[j][g]);
// W1/W2 staged in LDS. wab row: w0[0:64], b0[64], W1[65:4161], b1[4161:4225],
// W2[4225:8321], b2[8321:8385], w3[8385:8449], b3[8449]
__global__ __launch_bounds__(512) void decoder_kernel(const float* __restrict__ wab,
                                                      const float* __restrict__ logP,
                                                      float* __restrict__ out) {
    __shared__ __align__(16) float Wl[64 * 64];   // 16 KB staged W1 then W2
    __shared__ float hX[64 * GSTR];               // 16.6 KB, h[j][g]
    __shared__ float hY[64 * GSTR];
    __shared__ float red[8][68];
    int b   = blockIdx.x >> 1;
    int gbl = blockIdx.x & 1;
    int tid = threadIdx.x;
    int lane = tid & 63;
    int wid  = __builtin_amdgcn_readfirstlane(tid >> 6);  // 0..7
    int jq = wid * 8;
    int g = gbl * 64 + lane;
    bool act = g < 100;
    const float* __restrict__ row = wab + b * WSTRIDE;
    float x0 = act ? logP[b * 100 + g] * (1.0f / 3.0f) : 0.0f;

    // layer 0: h[j][g] = sin(30*(x0*w0[j] + b0)), j in this wave's eighth
    float c0 = row[64];
#pragma unroll
    for (int t = 0; t < 8; ++t)
        hX[(jq + t) * GSTR + lane] = __sinf(30.0f * fmaf(x0, row[jq + t], c0));
    // stage W1 (coalesced b32)
#pragma unroll
    for (int r = 0; r < 8; ++r) {
        int idx = r * 512 + tid;
        Wl[idx] = row[65 + idx];
    }
    __syncthreads();

    // layer 1: a[j] = sum_i h_i * W1[i][j]; read hX, write hY
    {
        float a[8];
#pragma unroll
        for (int t = 0; t < 8; ++t) a[t] = row[4161 + jq + t];
#pragma unroll 8
        for (int i = 0; i < 64; ++i) {
            float hi = hX[i * GSTR + lane];          // stride-1: conflict-free
            const float* wr = &Wl[i * 64 + jq];      // wave-uniform broadcast
            float4 w0 = *(const float4*)&wr[0];
            float4 w1 = *(const float4*)&wr[4];
            a[0] = fmaf(hi, w0.x, a[0]);  a[1] = fmaf(hi, w0.y, a[1]);
            a[2] = fmaf(hi, w0.z, a[2]);  a[3] = fmaf(hi, w0.w, a[3]);
            a[4] = fmaf(hi, w1.x, a[4]);  a[5] = fmaf(hi, w1.y, a[5]);
            a[6] = fmaf(hi, w1.z, a[6]);  a[7] = fmaf(hi, w1.w, a[7]);
        }
#pragma unroll
        for (int t = 0; t < 8; ++t) hY[(jq + t) * GSTR + lane] = __sinf(a[t]);
    }
    __syncthreads();
    // stage W2 over Wl
#pragma unroll
    for (int r = 0; r < 8; ++r) {
        int idx = r * 512 + tid;
        Wl[idx] = row[4225 + idx];
    }
    __syncthreads();

    // layer 2: read hY, write hX
    {
        float a[8];
#pragma unroll
        for (int t = 0; t < 8; ++t) a[t] = row[8321 + jq + t];
#pragma unroll 8
        for (int i = 0; i < 64; ++i) {
            float hi = hY[i * GSTR + lane];
            const float* wr = &Wl[i * 64 + jq];
            float4 w0 = *(const float4*)&wr[0];
            float4 w1 = *(const float4*)&wr[4];
            a[0] = fmaf(hi, w0.x, a[0]);  a[1] = fmaf(hi, w0.y, a[1]);
            a[2] = fmaf(hi, w0.z, a[2]);  a[3] = fmaf(hi, w0.w, a[3]);
            a[4] = fmaf(hi, w1.x, a[4]);  a[5] = fmaf(hi, w1.y, a[5]);
            a[6] = fmaf(hi, w1.z, a[6]);  a[7] = fmaf(hi, w1.w, a[7]);
        }
#pragma unroll
        for (int t = 0; t < 8; ++t) hX[(jq + t) * GSTR + lane] = __sinf(a[t]);
    }
    __syncthreads();

    // layer 3: partial dot over this wave's 8 j's, cross-wave reduce
    float p = 0.f;
#pragma unroll
    for (int t = 0; t < 8; ++t)
        p = fmaf(hX[(jq + t) * GSTR + lane], row[8385 + jq + t], p);
    red[wid][lane] = p;
    __syncthreads();
    if (wid == 0 && act) {
        float s = row[8449];
#pragma unroll
        for (int w = 0; w < 8; ++w) s += red[w][lane];
        out[b * 100 + g] = fmaf(s, 500.0f, 1500.0f);
    }
}

extern "C" void kernel_launch(void* const* d_in, const int* in_sizes, int n_in,
                              void* d_out, int out_size, void* d_ws, size_t ws_size,
                              hipStream_t stream) {
    const float* z    = (const float*)d_in[0];
    const float* logP = (const float*)d_in[1];
    const float* hW0  = (const float*)d_in[2];
    const float* hb0  = (const float*)d_in[3];
    const float* hW1  = (const float*)d_in[4];
    const float* hb1  = (const float*)d_in[5];
    const float* hW2  = (const float*)d_in[6];
    const float* hb2  = (const float*)d_in[7];
    const float* hWo  = (const float*)d_in[8];
    const float* hbo  = (const float*)d_in[9];
    float* out = (float*)d_out;

    float* wab = (float*)d_ws;               // 128*8704 floats
    float* h0T = wab + 128 * WSTRIDE;        // 512*128 floats (transposed)
    float* h1T = h0T + 512 * 128;
    float* h2T = h1T + 512 * 128;

    h0T_kernel<<<512, 128, 0, stream>>>(z, hW0, hb0, h0T);
    gemmT_kernel<<<256, 512, 0, stream>>>(h0T, hW1, hb1, h1T);
    gemmT_kernel<<<256, 512, 0, stream>>>(h1T, hW2, hb2, h2T);
    wabT_kernel<<<536, 256, 0, stream>>>(h2T, hWo, hbo, wab);
    decoder_kernel<<<256, 512, 0, stream>>>(wab, logP, out);
}